// Round 6
// baseline (977.940 us; speedup 1.0000x reference)
//
#include <hip/hip_runtime.h>
#include <stdint.h>

#define HIDDEN 4096
#define M_TOK 8192   // B*S
#define KDIM 4096

typedef __attribute__((ext_vector_type(8))) __bf16 bf16x8;
typedef __attribute__((ext_vector_type(4))) float f32x4;
typedef __attribute__((ext_vector_type(8))) unsigned short u16x8;

#define GAS __attribute__((address_space(1)))
#define LAS __attribute__((address_space(3)))

__device__ __forceinline__ unsigned short f2bf(float f) {
  unsigned int u = __float_as_uint(f);
  u += 0x7FFFu + ((u >> 16) & 1u);
  return (unsigned short)(u >> 16);
}
__device__ __forceinline__ float bf2f(unsigned short b) {
  return __uint_as_float(((unsigned int)b) << 16);
}

// ---------- fp32 -> bf16, 8 elems/thread ----------
__global__ __launch_bounds__(256) void cvt_kernel(const float* __restrict__ in,
                                                  unsigned short* __restrict__ out,
                                                  int n8) {
  int i = blockIdx.x * 256 + threadIdx.x;
  if (i >= n8) return;
  const f32x4* p = (const f32x4*)in + (size_t)2 * i;
  f32x4 a = p[0], b = p[1];
  u16x8 o;
  o[0] = f2bf(a.x); o[1] = f2bf(a.y); o[2] = f2bf(a.z); o[3] = f2bf(a.w);
  o[4] = f2bf(b.x); o[5] = f2bf(b.y); o[6] = f2bf(b.z); o[7] = f2bf(b.w);
  ((u16x8*)out)[i] = o;
}

// ============================================================================
// 128x128 QKV GEMM, BK=64, 2 blocks/CU (R5 post-mortem: 1-block/CU 256^2 was
// sync-bound at 56% MfmaUtil with HBM at 15% -- occupancy was the limiter).
// 512 thr = 8 waves (2M x 4N), per-wave 64x32 -> acc = 32 VGPR. LDS 64 KiB
// (A[2][128][64] + B[2][128][64]) -> 2 blocks/CU; __launch_bounds__(512,4)
// caps unified regs at 128 -> 16 waves/CU. Cross-BLOCK overlap fills barrier
// bubbles (m114 mechanism).
// LDS swizzle/read pattern: EXACTLY the R3 pattern (only one measured at 0
// conflicts; R1/R2/R4 variants all measured +4.0 cyc/read).
// Schedule per K-tile: reads(12) -> lgkm -> BAR1 -> stage t+2 into freed buf
// -> 16 MFMA (8 indep ks0, then 8 ks1) -> VMC4 -> BAR2. 2-deep prefetch;
// in-order vmcnt retirement makes VMC4+BAR2 guarantee t+1's staging visible
// to ALL waves before its reads.
// ============================================================================
#define BAR() __builtin_amdgcn_s_barrier()
#define PRIO(p) __builtin_amdgcn_s_setprio(p)
#define VMC4() asm volatile("s_waitcnt vmcnt(4)" ::: "memory")
#define VMC0() asm volatile("s_waitcnt vmcnt(0)" ::: "memory")
#define LGKM0() do { asm volatile("s_waitcnt lgkmcnt(0)" ::: "memory"); \
  __builtin_amdgcn_sched_barrier(0); } while (0)
#define SB0() __builtin_amdgcn_sched_barrier(0)

__global__ __launch_bounds__(512, 4) void gemm_qkv(
    const unsigned short* __restrict__ A,   // [8192][4096] bf16
    const unsigned short* __restrict__ W,   // [12288][4096] bf16 (wq;wk;wv)
    const float* __restrict__ bias,         // [12288]
    unsigned short* __restrict__ out) {     // [3][8192][4096] bf16
  __shared__ __attribute__((aligned(16))) unsigned short lds[32768];  // 64 KiB

  int tid = threadIdx.x;
  int lane = tid & 63;
  int w = tid >> 6;
  int wm = w >> 2;        // 0..1 -> rows wm*64
  int wn = w & 3;         // 0..3 -> cols wn*32
  int l16 = lane & 15;
  int lk = lane >> 4;

  // ---- 2D XCD slab mapping (grid = 6144 = 8 XCD * 8 tm * 96 tn) ----
  int bid = blockIdx.x;
  int xcd = bid & 7;
  int local = bid >> 3;       // 0..767
  int r = local >> 6;         // 0..11 tn-round
  int i = local & 63;         // 64 co-resident (2/CU * 32 CU) per XCD
  int tm = (xcd << 3) + (i >> 3);   // 8 tm rows per XCD slab
  int tn = (r << 3) + (i & 7);      // 8 tn cols per round
  int m0 = tm << 7, n0 = tn << 7;

  // ---- staging source: pre-swizzled global col (3-bit XOR by row&7) ----
  int rp = tid >> 3;                                     // 0..63
  int ce = ((tid & 7) << 3) ^ ((rp & 7) << 3);           // col elems, swizzled
  const unsigned short* aSrc = A + (size_t)(m0 + rp) * KDIM + ce;
  const unsigned short* bSrc = W + (size_t)(n0 + rp) * KDIM + ce;
  int tid8 = tid * 8;

  // LDS shorts layout: A buf b at b*8192 ([128][64]); B at 16384 + b*8192.
#define STA(b, kt) do { \
  __builtin_amdgcn_global_load_lds((GAS void*)(aSrc + (kt)*64), \
      (LAS void*)(lds + (b)*8192 + tid8), 16, 0, 0); \
  __builtin_amdgcn_global_load_lds((GAS void*)(aSrc + (size_t)64 * KDIM + (kt)*64), \
      (LAS void*)(lds + (b)*8192 + 4096 + tid8), 16, 0, 0); } while (0)
#define STB(b, kt) do { \
  __builtin_amdgcn_global_load_lds((GAS void*)(bSrc + (kt)*64), \
      (LAS void*)(lds + 16384 + (b)*8192 + tid8), 16, 0, 0); \
  __builtin_amdgcn_global_load_lds((GAS void*)(bSrc + (size_t)64 * KDIM + (kt)*64), \
      (LAS void*)(lds + 16384 + (b)*8192 + 4096 + tid8), 16, 0, 0); } while (0)

  // ---- fragment read addressing: R3 pattern (0 conflicts measured) ----
  int colbase = (lk << 3) ^ ((l16 & 7) << 3);
  int aRd = wm * 4096 + l16 * 64 + colbase;            // rows wm*64 + mi*16 + l16
  int bRd = wn * 2048 + l16 * 64 + colbase;            // rows wn*32 + nj*16 + l16

#define RD_A(c, mi, ks) (*(const bf16x8*)(lds + (c)*8192 + (((aRd) + (mi)*1024) ^ ((ks)*32))))
#define RD_B(c, nj, ks) (*(const bf16x8*)(lds + 16384 + (c)*8192 + (((bRd) + (nj)*1024) ^ ((ks)*32))))

  bf16x8 av[4][2];
  bf16x8 bv[2][2];
  f32x4 acc[4][2] = {};

#define READS(c) do { \
  bv[0][0]=RD_B(c,0,0); bv[0][1]=RD_B(c,0,1); bv[1][0]=RD_B(c,1,0); bv[1][1]=RD_B(c,1,1); \
  av[0][0]=RD_A(c,0,0); av[0][1]=RD_A(c,0,1); av[1][0]=RD_A(c,1,0); av[1][1]=RD_A(c,1,1); \
  av[2][0]=RD_A(c,2,0); av[2][1]=RD_A(c,2,1); av[3][0]=RD_A(c,3,0); av[3][1]=RD_A(c,3,1); } while (0)

#define MF(mi, nj, ks) acc[mi][nj] = __builtin_amdgcn_mfma_f32_16x16x32_bf16( \
    av[mi][ks], bv[nj][ks], acc[mi][nj], 0, 0, 0)
  // 8 independent (ks0), then 8 (ks1, dep 8 apart)
#define MFMAS() do { \
  MF(0,0,0); MF(0,1,0); MF(1,0,0); MF(1,1,0); MF(2,0,0); MF(2,1,0); MF(3,0,0); MF(3,1,0); \
  MF(0,0,1); MF(0,1,1); MF(1,0,1); MF(1,1,1); MF(2,0,1); MF(2,1,1); MF(3,0,1); MF(3,1,1); } while (0)

  // ---- prologue: stage kt0 -> buf0, kt1 -> buf1 ----
  STA(0, 0); STB(0, 0); STA(1, 1); STB(1, 1);
  VMC0();
  BAR();

  // ---- main loop: 31 iters x 2 K-tiles (kt 0..61), then tails 62, 63 ----
  for (int it = 0; it < 31; ++it) {
    int k2 = 2 * it + 2, k3 = 2 * it + 3;
    // kt = 2it, buf0
    READS(0); LGKM0(); BAR();
    STA(0, k2); STB(0, k2); SB0();
    PRIO(1); MFMAS(); PRIO(0);
    VMC4(); BAR();
    // kt = 2it+1, buf1
    READS(1); LGKM0(); BAR();
    STA(1, k3); STB(1, k3); SB0();
    PRIO(1); MFMAS(); PRIO(0);
    VMC4(); BAR();
  }
  // kt = 62, buf0 (no stage; drain so kt63's staging is landed for everyone)
  READS(0); LGKM0(); BAR();
  PRIO(1); MFMAS(); PRIO(0);
  VMC0(); BAR();
  // kt = 63, buf1
  READS(1); LGKM0(); BAR();
  PRIO(1); MFMAS(); PRIO(0);

  // ---- C write: col = l16 + 16*nj (+ wn*32), row = lk*4 + rr + 16*mi (+ wm*64) ----
  int matc = n0 >> 12;
  int ncol = (n0 & 4095) + wn * 32;
  unsigned short* O = out + (size_t)matc * M_TOK * HIDDEN;
  float bb0 = bias[n0 + wn * 32 + l16];
  float bb1 = bias[n0 + wn * 32 + 16 + l16];
#pragma unroll
  for (int mi = 0; mi < 4; ++mi) {
#pragma unroll
    for (int rr = 0; rr < 4; ++rr) {
      int row = m0 + wm * 64 + mi * 16 + lk * 4 + rr;
      size_t rb = (size_t)row * HIDDEN + ncol + l16;
      O[rb] = f2bf(acc[mi][0][rr] + bb0);
      O[rb + 16] = f2bf(acc[mi][1][rr] + bb1);
    }
  }
}

// ---------- per-token 32x32 head attention ----------
__global__ __launch_bounds__(256) void attn_kernel(const unsigned short* __restrict__ qkv,
                                                   float* __restrict__ out) {
  __shared__ float sQ[32 * 132];
  __shared__ float sK[32 * 132];
  __shared__ float sV[32 * 132];
  __shared__ float sP[32 * 33];

  int m = blockIdx.x;
  int tid = threadIdx.x;
  const unsigned short* gq = qkv + (size_t)m * HIDDEN;
  const unsigned short* gk = gq + (size_t)M_TOK * HIDDEN;
  const unsigned short* gv = gk + (size_t)M_TOK * HIDDEN;

  int row = tid >> 3;
  int cb = (tid & 7) << 4;
  int go = row * 128 + cb;
  int lo = row * 132 + cb;
  {
    u16x8 x0 = *(const u16x8*)(gq + go);
    u16x8 x1 = *(const u16x8*)(gq + go + 8);
#pragma unroll
    for (int j = 0; j < 8; ++j) { sQ[lo + j] = bf2f(x0[j]); sQ[lo + 8 + j] = bf2f(x1[j]); }
    x0 = *(const u16x8*)(gk + go);
    x1 = *(const u16x8*)(gk + go + 8);
#pragma unroll
    for (int j = 0; j < 8; ++j) { sK[lo + j] = bf2f(x0[j]); sK[lo + 8 + j] = bf2f(x1[j]); }
    x0 = *(const u16x8*)(gv + go);
    x1 = *(const u16x8*)(gv + go + 8);
#pragma unroll
    for (int j = 0; j < 8; ++j) { sV[lo + j] = bf2f(x0[j]); sV[lo + 8 + j] = bf2f(x1[j]); }
  }
  __syncthreads();

  int h = tid >> 3;
  int t4 = (tid & 7) << 2;
  const f32x4* qr = (const f32x4*)(sQ + h * 132);
  const f32x4* k0 = (const f32x4*)(sK + (t4 + 0) * 132);
  const f32x4* k1 = (const f32x4*)(sK + (t4 + 1) * 132);
  const f32x4* k2 = (const f32x4*)(sK + (t4 + 2) * 132);
  const f32x4* k3 = (const f32x4*)(sK + (t4 + 3) * 132);
  float s0 = 0.f, s1 = 0.f, s2 = 0.f, s3 = 0.f;
#pragma unroll
  for (int d = 0; d < 32; ++d) {
    f32x4 q = qr[d];
    f32x4 a = k0[d]; s0 += q.x * a.x + q.y * a.y + q.z * a.z + q.w * a.w;
    f32x4 b = k1[d]; s1 += q.x * b.x + q.y * b.y + q.z * b.z + q.w * b.w;
    f32x4 c = k2[d]; s2 += q.x * c.x + q.y * c.y + q.z * c.z + q.w * c.w;
    f32x4 e = k3[d]; s3 += q.x * e.x + q.y * e.y + q.z * e.z + q.w * e.w;
  }
  const float scale = 0.08838834764831845f;  // 1/sqrt(128)
  s0 *= scale; s1 *= scale; s2 *= scale; s3 *= scale;
  float mx = fmaxf(fmaxf(s0, s1), fmaxf(s2, s3));
  mx = fmaxf(mx, __shfl_xor(mx, 1));
  mx = fmaxf(mx, __shfl_xor(mx, 2));
  mx = fmaxf(mx, __shfl_xor(mx, 4));
  float e0 = __expf(s0 - mx), e1 = __expf(s1 - mx), e2 = __expf(s2 - mx), e3 = __expf(s3 - mx);
  float sum = e0 + e1 + e2 + e3;
  sum += __shfl_xor(sum, 1);
  sum += __shfl_xor(sum, 2);
  sum += __shfl_xor(sum, 4);
  float inv = 1.0f / sum;
  sP[h * 33 + t4 + 0] = e0 * inv;
  sP[h * 33 + t4 + 1] = e1 * inv;
  sP[h * 33 + t4 + 2] = e2 * inv;
  sP[h * 33 + t4 + 3] = e3 * inv;
  __syncthreads();

  int d0 = (tid & 7) << 4;
  f32x4 o0 = {0.f, 0.f, 0.f, 0.f}, o1 = o0, o2 = o0, o3 = o0;
  const float* pr = sP + h * 33;
#pragma unroll
  for (int t = 0; t < 32; ++t) {
    float p = pr[t];
    const f32x4* vr = (const f32x4*)(sV + t * 132 + d0);
    o0 += p * vr[0];
    o1 += p * vr[1];
    o2 += p * vr[2];
    o3 += p * vr[3];
  }
  f32x4* op = (f32x4*)(out + (size_t)m * HIDDEN + h * 128 + d0);
  op[0] = o0; op[1] = o1; op[2] = o2; op[3] = o3;
}

extern "C" void kernel_launch(void* const* d_in, const int* in_sizes, int n_in,
                              void* d_out, int out_size, void* d_ws, size_t ws_size,
                              hipStream_t stream) {
  const float* hs = (const float*)d_in[0];
  const float* wq = (const float*)d_in[1];
  const float* bq = (const float*)d_in[2];
  const float* wk = (const float*)d_in[3];
  const float* bk = (const float*)d_in[4];
  const float* wv = (const float*)d_in[5];
  const float* bv = (const float*)d_in[6];
  // wl/bl latent projection: unused by output — skipped.

  char* ws = (char*)d_ws;
  const size_t HS_OFF = 0;                    // 64 MiB
  const size_t W_OFF = 67108864;              // 96 MiB
  const size_t QKV_OFF = 167772160;           // 192 MiB
  const size_t BIAS_OFF = 369098752;          // 48 KiB
  const size_t NEED = 369147904;
  if (ws_size < NEED) return;

  unsigned short* hsb = (unsigned short*)(ws + HS_OFF);
  unsigned short* wb = (unsigned short*)(ws + W_OFF);
  unsigned short* qkv = (unsigned short*)(ws + QKV_OFF);
  float* bias = (float*)(ws + BIAS_OFF);

  cvt_kernel<<<16384, 256, 0, stream>>>(hs, hsb, 4194304);
  cvt_kernel<<<8192, 256, 0, stream>>>(wq, wb, 2097152);
  cvt_kernel<<<8192, 256, 0, stream>>>(wk, wb + 16777216, 2097152);
  cvt_kernel<<<8192, 256, 0, stream>>>(wv, wb + 33554432, 2097152);
  hipMemcpyAsync(bias, bq, 16384, hipMemcpyDeviceToDevice, stream);
  hipMemcpyAsync(bias + 4096, bk, 16384, hipMemcpyDeviceToDevice, stream);
  hipMemcpyAsync(bias + 8192, bv, 16384, hipMemcpyDeviceToDevice, stream);

  gemm_qkv<<<6144, 512, 0, stream>>>(hsb, wb, bias, qkv);   // 8 XCD x 8 tm x 96 tn
  attn_kernel<<<8192, 256, 0, stream>>>(qkv, (float*)d_out);
}

// Round 7
// 864.972 us; speedup vs baseline: 1.1306x; 1.1306x over previous
//
#include <hip/hip_runtime.h>
#include <stdint.h>

#define HIDDEN 4096
#define M_TOK 8192   // B*S
#define KDIM 4096

typedef __attribute__((ext_vector_type(8))) __bf16 bf16x8;
typedef __attribute__((ext_vector_type(4))) float f32x4;
typedef __attribute__((ext_vector_type(8))) unsigned short u16x8;

#define GAS __attribute__((address_space(1)))
#define LAS __attribute__((address_space(3)))

__device__ __forceinline__ unsigned short f2bf(float f) {
  unsigned int u = __float_as_uint(f);
  u += 0x7FFFu + ((u >> 16) & 1u);
  return (unsigned short)(u >> 16);
}
__device__ __forceinline__ float bf2f(unsigned short b) {
  return __uint_as_float(((unsigned int)b) << 16);
}

// ---------- fused fp32->bf16 conversions + bias pack, one launch ----------
__device__ __forceinline__ void cvt8(const float* __restrict__ in,
                                     unsigned short* __restrict__ out, int i) {
  const f32x4* p = (const f32x4*)in + (size_t)2 * i;
  f32x4 a = p[0], b = p[1];
  u16x8 o;
  o[0] = f2bf(a.x); o[1] = f2bf(a.y); o[2] = f2bf(a.z); o[3] = f2bf(a.w);
  o[4] = f2bf(b.x); o[5] = f2bf(b.y); o[6] = f2bf(b.z); o[7] = f2bf(b.w);
  ((u16x8*)out)[i] = o;
}

__global__ __launch_bounds__(256) void cvt_fused(
    const float* __restrict__ hs, const float* __restrict__ wq,
    const float* __restrict__ wk, const float* __restrict__ wv,
    const float* __restrict__ bq, const float* __restrict__ bk,
    const float* __restrict__ bv,
    unsigned short* __restrict__ hsb, unsigned short* __restrict__ wb,
    float* __restrict__ bias) {
  int b = blockIdx.x;
  int tid = threadIdx.x;
  if (b < 16384) {                      // hs: 33.5M elems
    cvt8(hs, hsb, b * 256 + tid);
  } else if (b < 24576) {               // wq
    cvt8(wq, wb, (b - 16384) * 256 + tid);
  } else if (b < 32768) {               // wk
    cvt8(wk, wb + 16777216, (b - 24576) * 256 + tid);
  } else if (b < 40960) {               // wv
    cvt8(wv, wb + 33554432, (b - 32768) * 256 + tid);
  } else {                              // bias pack: 48 blocks x 256 = 12288
    int i = (b - 40960) * 256 + tid;
    float v = (i < 4096) ? bq[i] : (i < 8192) ? bk[i - 4096] : bv[i - 8192];
    bias[i] = v;
  }
}

// ============================================================================
// 256x256 8-phase QKV GEMM (R5 structure: 16x16x32 MFMA, 0 bank conflicts,
// 2D XCD slab map) + COUNTED-LGKM READ-AHEAD (R6 post-mortem: 128^2/2-block
// was LDS-BW-bound -> 256^2 is the right tile; residual stall is each phase's
// serial ds_read->lgkm0->MFMA chain).
// Reads shifted one phase early: P1 issues RP1+RP2, waits lgkmcnt(8) (RP1
// retired; RP2 hides under MM0/MM1); P2 issues RP3, waits lgkmcnt(4); P3
// waits lgkmcnt(0); P4 no wait. gload_lds touches vmcnt only, so lgkm counts
// are exactly our ds_reads. Stage placement / vmcnt(6) cadence / barriers
// IDENTICAL to R5 (verified), WAR invariant preserved (reads retire earlier).
// ============================================================================
#define BAR() __builtin_amdgcn_s_barrier()
#define PRIO(p) __builtin_amdgcn_s_setprio(p)
#define VMC6() asm volatile("s_waitcnt vmcnt(6)" ::: "memory")
#define VMC4() asm volatile("s_waitcnt vmcnt(4)" ::: "memory")
#define VMC0() asm volatile("s_waitcnt vmcnt(0)" ::: "memory")
#define LGKM(n) do { asm volatile("s_waitcnt lgkmcnt(" #n ")" ::: "memory"); \
  __builtin_amdgcn_sched_barrier(0); } while (0)
#define SB0() __builtin_amdgcn_sched_barrier(0)

__global__ __launch_bounds__(512, 2) void gemm_qkv(
    const unsigned short* __restrict__ A,   // [8192][4096] bf16
    const unsigned short* __restrict__ W,   // [12288][4096] bf16 (wq;wk;wv)
    const float* __restrict__ bias,         // [12288]
    unsigned short* __restrict__ out) {     // [3][8192][4096] bf16
  __shared__ __attribute__((aligned(16))) unsigned short lds[65536];  // 128 KiB

  int tid = threadIdx.x;
  int lane = tid & 63;
  int w = tid >> 6;
  int wm = w >> 2;        // 0..1 -> rows wm*128
  int wn = w & 3;         // 0..3 -> cols wn*64
  int l16 = lane & 15;
  int lk = lane >> 4;

  // ---- 2D XCD slab mapping (bijective; grid = 1536 = 8 XCD * 4 tm * 48 tn) ----
  int bid = blockIdx.x;
  int xcd = bid & 7;
  int local = bid >> 3;       // 0..191
  int r = local >> 5;         // 0..5 tn-round
  int i = local & 31;         // 0..31 co-resident slot
  int tm = (xcd << 2) + (i >> 3);
  int tn = (r << 3) + (i & 7);
  int m0 = tm << 8, n0 = tn << 8;

  // ---- staging source: pre-swizzled global col (3-bit XOR by row&7) ----
  int rp = tid >> 3;
  int ce = ((tid & 7) << 3) ^ ((rp & 7) << 3);
  const unsigned short* aSrc = A + (size_t)(m0 + rp) * KDIM + ce;
  const unsigned short* bSrc = W + (size_t)(n0 + rp) * KDIM + ce;
  int tid8 = tid * 8;

#define STA(b, h, kt) do { \
  __builtin_amdgcn_global_load_lds((GAS void*)(aSrc + (size_t)((h)*128) * KDIM + (kt)*64), \
      (LAS void*)(lds + (b)*16384 + (h)*8192 + tid8), 16, 0, 0); \
  __builtin_amdgcn_global_load_lds((GAS void*)(aSrc + (size_t)((h)*128 + 64) * KDIM + (kt)*64), \
      (LAS void*)(lds + (b)*16384 + (h)*8192 + 4096 + tid8), 16, 0, 0); } while (0)
#define STB(b, h, kt) do { \
  __builtin_amdgcn_global_load_lds((GAS void*)(bSrc + (size_t)((h)*128) * KDIM + (kt)*64), \
      (LAS void*)(lds + 32768 + (b)*16384 + (h)*8192 + tid8), 16, 0, 0); \
  __builtin_amdgcn_global_load_lds((GAS void*)(bSrc + (size_t)((h)*128 + 64) * KDIM + (kt)*64), \
      (LAS void*)(lds + 32768 + (b)*16384 + (h)*8192 + 4096 + tid8), 16, 0, 0); } while (0)

  // ---- fragment read addressing: R3 pattern (0 conflicts measured) ----
  int colbase = (lk << 3) ^ ((l16 & 7) << 3);
  int aRd = wm * 8192 + l16 * 64 + colbase;
  int bRd = (wn >> 1) * 8192 + (wn & 1) * 4096 + l16 * 64 + colbase;

#define RD_A(c, mi, ks) (*(const bf16x8*)(lds + (c)*16384 + (((aRd) + (mi)*1024) ^ ((ks)*32))))
#define RD_B(c, nj, ks) (*(const bf16x8*)(lds + 32768 + (c)*16384 + (((bRd) + (nj)*1024) ^ ((ks)*32))))

  bf16x8 av[8][2];
  bf16x8 bv[4][2];
  f32x4 acc[8][4] = {};

#define RP1(c) do { \
  bv[0][0]=RD_B(c,0,0); bv[0][1]=RD_B(c,0,1); bv[1][0]=RD_B(c,1,0); bv[1][1]=RD_B(c,1,1); \
  bv[2][0]=RD_B(c,2,0); bv[2][1]=RD_B(c,2,1); bv[3][0]=RD_B(c,3,0); bv[3][1]=RD_B(c,3,1); \
  av[0][0]=RD_A(c,0,0); av[0][1]=RD_A(c,0,1); av[1][0]=RD_A(c,1,0); av[1][1]=RD_A(c,1,1); } while (0)
#define RP2(c) do { \
  av[2][0]=RD_A(c,2,0); av[2][1]=RD_A(c,2,1); av[3][0]=RD_A(c,3,0); av[3][1]=RD_A(c,3,1); \
  av[4][0]=RD_A(c,4,0); av[4][1]=RD_A(c,4,1); av[5][0]=RD_A(c,5,0); av[5][1]=RD_A(c,5,1); } while (0)
#define RP3(c) do { \
  av[6][0]=RD_A(c,6,0); av[6][1]=RD_A(c,6,1); av[7][0]=RD_A(c,7,0); av[7][1]=RD_A(c,7,1); } while (0)

#define MFMA2(mi, nj) do { \
  acc[mi][nj] = __builtin_amdgcn_mfma_f32_16x16x32_bf16(av[mi][0], bv[nj][0], acc[mi][nj], 0, 0, 0); \
  acc[mi][nj] = __builtin_amdgcn_mfma_f32_16x16x32_bf16(av[mi][1], bv[nj][1], acc[mi][nj], 0, 0, 0); } while (0)
#define MM(mi) do { MFMA2(mi,0); MFMA2(mi,1); MFMA2(mi,2); MFMA2(mi,3); } while (0)

  // One K-tile with read-ahead. c = buffer, ka = kt staged into !c A1 at P1,
  // kb = kt staged into c (B0,B1,A0) at P2..P4.  (Matches R5 stage order.)
#define KTILE(c, ka, kb) do { \
  RP1(c); RP2(c); STA(!(c), 1, ka); \
  BAR(); LGKM(8); PRIO(1); MM(0); MM(1); PRIO(0); BAR(); \
  RP3(c); STB(c, 0, kb); \
  BAR(); LGKM(4); PRIO(1); MM(2); MM(3); PRIO(0); BAR(); \
  STB(c, 1, kb); \
  BAR(); LGKM(0); PRIO(1); MM(4); MM(5); PRIO(0); BAR(); \
  STA(c, 0, kb); \
  BAR(); SB0(); PRIO(1); MM(6); MM(7); PRIO(0); VMC6(); BAR(); } while (0)

  // ---- prologue: kt0 full (B0,B1,A0,A1) + kt1 (B0,B1,A0); 6 loads in flight ----
  STB(0, 0, 0); STB(0, 1, 0); STA(0, 0, 0); STA(0, 1, 0);
  VMC4();
  STB(1, 0, 1); STB(1, 1, 1); STA(1, 0, 1);
  VMC6();
  BAR();

  // ---- main loop: 31 iters x 2 K-tiles (kt 0..61) ----
  for (int it = 0; it < 31; ++it) {
    int k1 = 2 * it + 1, k2 = 2 * it + 2, k3 = 2 * it + 3;
    KTILE(0, k1, k2);
    KTILE(1, k2, k3);
  }
  // ---- epilogue: kt62 (buf0; stage only A1 of kt63; drain), kt63 (buf1) ----
  RP1(0); RP2(0); STA(1, 1, 63);
  BAR(); LGKM(8); PRIO(1); MM(0); MM(1); PRIO(0); BAR();
  RP3(0);
  BAR(); LGKM(4); PRIO(1); MM(2); MM(3); PRIO(0); BAR();
  BAR(); LGKM(0); PRIO(1); MM(4); MM(5); PRIO(0); BAR();
  BAR(); SB0(); PRIO(1); MM(6); MM(7); PRIO(0); VMC0(); BAR();
  RP1(1); RP2(1);
  BAR(); LGKM(8); PRIO(1); MM(0); MM(1); PRIO(0); BAR();
  RP3(1);
  BAR(); LGKM(4); PRIO(1); MM(2); MM(3); PRIO(0); BAR();
  BAR(); LGKM(0); PRIO(1); MM(4); MM(5); PRIO(0); BAR();
  BAR(); SB0(); PRIO(1); MM(6); MM(7); PRIO(0);

  // ---- C write: col = l16 + 16*nj (+ wn*64), row = lk*4 + r + 16*mi (+ wm*128) ----
  int matc = n0 >> 12;
  int ncol = (n0 & 4095) + wn * 64;
  unsigned short* O = out + (size_t)matc * M_TOK * HIDDEN;
  float bb[4];
#pragma unroll
  for (int nj = 0; nj < 4; ++nj) bb[nj] = bias[n0 + wn * 64 + nj * 16 + l16];
#pragma unroll
  for (int mi = 0; mi < 8; ++mi) {
#pragma unroll
    for (int rr = 0; rr < 4; ++rr) {
      int row = m0 + wm * 128 + mi * 16 + lk * 4 + rr;
      size_t rb = (size_t)row * HIDDEN + ncol + l16;
#pragma unroll
      for (int nj = 0; nj < 4; ++nj)
        O[rb + nj * 16] = f2bf(acc[mi][nj][rr] + bb[nj]);
    }
  }
}

// ---------- per-token 32x32 head attention ----------
__global__ __launch_bounds__(256) void attn_kernel(const unsigned short* __restrict__ qkv,
                                                   float* __restrict__ out) {
  __shared__ float sQ[32 * 132];
  __shared__ float sK[32 * 132];
  __shared__ float sV[32 * 132];
  __shared__ float sP[32 * 33];

  int m = blockIdx.x;
  int tid = threadIdx.x;
  const unsigned short* gq = qkv + (size_t)m * HIDDEN;
  const unsigned short* gk = gq + (size_t)M_TOK * HIDDEN;
  const unsigned short* gv = gk + (size_t)M_TOK * HIDDEN;

  int row = tid >> 3;
  int cb = (tid & 7) << 4;
  int go = row * 128 + cb;
  int lo = row * 132 + cb;
  {
    u16x8 x0 = *(const u16x8*)(gq + go);
    u16x8 x1 = *(const u16x8*)(gq + go + 8);
#pragma unroll
    for (int j = 0; j < 8; ++j) { sQ[lo + j] = bf2f(x0[j]); sQ[lo + 8 + j] = bf2f(x1[j]); }
    x0 = *(const u16x8*)(gk + go);
    x1 = *(const u16x8*)(gk + go + 8);
#pragma unroll
    for (int j = 0; j < 8; ++j) { sK[lo + j] = bf2f(x0[j]); sK[lo + 8 + j] = bf2f(x1[j]); }
    x0 = *(const u16x8*)(gv + go);
    x1 = *(const u16x8*)(gv + go + 8);
#pragma unroll
    for (int j = 0; j < 8; ++j) { sV[lo + j] = bf2f(x0[j]); sV[lo + 8 + j] = bf2f(x1[j]); }
  }
  __syncthreads();

  int h = tid >> 3;
  int t4 = (tid & 7) << 2;
  const f32x4* qr = (const f32x4*)(sQ + h * 132);
  const f32x4* k0 = (const f32x4*)(sK + (t4 + 0) * 132);
  const f32x4* k1 = (const f32x4*)(sK + (t4 + 1) * 132);
  const f32x4* k2 = (const f32x4*)(sK + (t4 + 2) * 132);
  const f32x4* k3 = (const f32x4*)(sK + (t4 + 3) * 132);
  float s0 = 0.f, s1 = 0.f, s2 = 0.f, s3 = 0.f;
#pragma unroll
  for (int d = 0; d < 32; ++d) {
    f32x4 q = qr[d];
    f32x4 a = k0[d]; s0 += q.x * a.x + q.y * a.y + q.z * a.z + q.w * a.w;
    f32x4 b = k1[d]; s1 += q.x * b.x + q.y * b.y + q.z * b.z + q.w * b.w;
    f32x4 c = k2[d]; s2 += q.x * c.x + q.y * c.y + q.z * c.z + q.w * c.w;
    f32x4 e = k3[d]; s3 += q.x * e.x + q.y * e.y + q.z * e.z + q.w * e.w;
  }
  const float scale = 0.08838834764831845f;  // 1/sqrt(128)
  s0 *= scale; s1 *= scale; s2 *= scale; s3 *= scale;
  float mx = fmaxf(fmaxf(s0, s1), fmaxf(s2, s3));
  mx = fmaxf(mx, __shfl_xor(mx, 1));
  mx = fmaxf(mx, __shfl_xor(mx, 2));
  mx = fmaxf(mx, __shfl_xor(mx, 4));
  float e0 = __expf(s0 - mx), e1 = __expf(s1 - mx), e2 = __expf(s2 - mx), e3 = __expf(s3 - mx);
  float sum = e0 + e1 + e2 + e3;
  sum += __shfl_xor(sum, 1);
  sum += __shfl_xor(sum, 2);
  sum += __shfl_xor(sum, 4);
  float inv = 1.0f / sum;
  sP[h * 33 + t4 + 0] = e0 * inv;
  sP[h * 33 + t4 + 1] = e1 * inv;
  sP[h * 33 + t4 + 2] = e2 * inv;
  sP[h * 33 + t4 + 3] = e3 * inv;
  __syncthreads();

  int d0 = (tid & 7) << 4;
  f32x4 o0 = {0.f, 0.f, 0.f, 0.f}, o1 = o0, o2 = o0, o3 = o0;
  const float* pr = sP + h * 33;
#pragma unroll
  for (int t = 0; t < 32; ++t) {
    float p = pr[t];
    const f32x4* vr = (const f32x4*)(sV + t * 132 + d0);
    o0 += p * vr[0];
    o1 += p * vr[1];
    o2 += p * vr[2];
    o3 += p * vr[3];
  }
  f32x4* op = (f32x4*)(out + (size_t)m * HIDDEN + h * 128 + d0);
  op[0] = o0; op[1] = o1; op[2] = o2; op[3] = o3;
}

extern "C" void kernel_launch(void* const* d_in, const int* in_sizes, int n_in,
                              void* d_out, int out_size, void* d_ws, size_t ws_size,
                              hipStream_t stream) {
  const float* hs = (const float*)d_in[0];
  const float* wq = (const float*)d_in[1];
  const float* bq = (const float*)d_in[2];
  const float* wk = (const float*)d_in[3];
  const float* bk = (const float*)d_in[4];
  const float* wv = (const float*)d_in[5];
  const float* bv = (const float*)d_in[6];
  // wl/bl latent projection: unused by output — skipped.

  char* ws = (char*)d_ws;
  const size_t HS_OFF = 0;                    // 64 MiB
  const size_t W_OFF = 67108864;              // 96 MiB
  const size_t QKV_OFF = 167772160;           // 192 MiB
  const size_t BIAS_OFF = 369098752;          // 48 KiB
  const size_t NEED = 369147904;
  if (ws_size < NEED) return;

  unsigned short* hsb = (unsigned short*)(ws + HS_OFF);
  unsigned short* wb = (unsigned short*)(ws + W_OFF);
  unsigned short* qkv = (unsigned short*)(ws + QKV_OFF);
  float* bias = (float*)(ws + BIAS_OFF);

  cvt_fused<<<41008, 256, 0, stream>>>(hs, wq, wk, wv, bq, bk, bv, hsb, wb, bias);
  gemm_qkv<<<1536, 512, 0, stream>>>(hsb, wb, bias, qkv);   // 8 XCD x 4 tm x 48 tn
  attn_kernel<<<8192, 256, 0, stream>>>(qkv, (float*)d_out);
}

// Round 8
// 838.196 us; speedup vs baseline: 1.1667x; 1.0319x over previous
//
#include <hip/hip_runtime.h>
#include <stdint.h>

#define HIDDEN 4096
#define M_TOK 8192   // B*S
#define KDIM 4096

typedef __attribute__((ext_vector_type(8))) __bf16 bf16x8;
typedef __attribute__((ext_vector_type(4))) float f32x4;
typedef __attribute__((ext_vector_type(8))) unsigned short u16x8;

#define GAS __attribute__((address_space(1)))
#define LAS __attribute__((address_space(3)))

__device__ __forceinline__ unsigned short f2bf(float f) {
  unsigned int u = __float_as_uint(f);
  u += 0x7FFFu + ((u >> 16) & 1u);
  return (unsigned short)(u >> 16);
}
__device__ __forceinline__ float bf2f(unsigned short b) {
  return __uint_as_float(((unsigned int)b) << 16);
}

// ---------- fused fp32->bf16 conversions + bias pack, one launch ----------
__device__ __forceinline__ void cvt8(const float* __restrict__ in,
                                     unsigned short* __restrict__ out, int i) {
  const f32x4* p = (const f32x4*)in + (size_t)2 * i;
  f32x4 a = p[0], b = p[1];
  u16x8 o;
  o[0] = f2bf(a.x); o[1] = f2bf(a.y); o[2] = f2bf(a.z); o[3] = f2bf(a.w);
  o[4] = f2bf(b.x); o[5] = f2bf(b.y); o[6] = f2bf(b.z); o[7] = f2bf(b.w);
  ((u16x8*)out)[i] = o;
}

__global__ __launch_bounds__(256) void cvt_fused(
    const float* __restrict__ hs, const float* __restrict__ wq,
    const float* __restrict__ wk, const float* __restrict__ wv,
    const float* __restrict__ bq, const float* __restrict__ bk,
    const float* __restrict__ bv,
    unsigned short* __restrict__ hsb, unsigned short* __restrict__ wb,
    float* __restrict__ bias) {
  int b = blockIdx.x;
  int tid = threadIdx.x;
  if (b < 16384) {                      // hs: 33.5M elems
    cvt8(hs, hsb, b * 256 + tid);
  } else if (b < 24576) {               // wq
    cvt8(wq, wb, (b - 16384) * 256 + tid);
  } else if (b < 32768) {               // wk
    cvt8(wk, wb + 16777216, (b - 24576) * 256 + tid);
  } else if (b < 40960) {               // wv
    cvt8(wv, wb + 33554432, (b - 32768) * 256 + tid);
  } else {                              // bias pack: 48 blocks x 256 = 12288
    int i = (b - 40960) * 256 + tid;
    float v = (i < 4096) ? bq[i] : (i < 8192) ? bk[i - 4096] : bv[i - 8192];
    bias[i] = v;
  }
}

// ============================================================================
// 256x256 QKV GEMM — R5 structure (16x16x32 MFMA, 0 bank conflicts, 2D XCD
// slab map) + IN-WINDOW READ PREFETCH (R7 post-mortem, corrected units):
// MFMA=2483 cyc/K-tile/CU, LDS=~1000, measured 4281 -> the gap is phase
// serialization: reads were issued BETWEEN barriers, so each phase =
// [read-service] then [MFMA], sequential. Fix: issue phase p+1's reads INSIDE
// phase p's MFMA window (post-MFMA-issue, sched_barrier-pinned), lgkmcnt(0)
// at phase open. P4->P1 hop: vmcnt(6) after P4's stage-issue retires exactly
// through A1(!c) (6 younger gloads follow); VMC6 BEFORE P4's open-barrier
// makes it an all-waves guarantee, so RP1(!c) inside P4 is race-free.
// WAR audit: every staged region's readers retire >=1 phase before the stage
// (P3 has LGKM(0) to close RP3-vs-STA(c,A0)). Stage slots + VMC6 cadence
// IDENTICAL to R5 (verified).
// ============================================================================
#define BAR() __builtin_amdgcn_s_barrier()
#define PRIO(p) __builtin_amdgcn_s_setprio(p)
#define VMC6() asm volatile("s_waitcnt vmcnt(6)" ::: "memory")
#define VMC0() asm volatile("s_waitcnt vmcnt(0)" ::: "memory")
#define LGKM0() do { asm volatile("s_waitcnt lgkmcnt(0)" ::: "memory"); \
  __builtin_amdgcn_sched_barrier(0); } while (0)
#define SB0() __builtin_amdgcn_sched_barrier(0)

__global__ __launch_bounds__(512, 2) void gemm_qkv(
    const unsigned short* __restrict__ A,   // [8192][4096] bf16
    const unsigned short* __restrict__ W,   // [12288][4096] bf16 (wq;wk;wv)
    const float* __restrict__ bias,         // [12288]
    unsigned short* __restrict__ out) {     // [3][8192][4096] bf16
  __shared__ __attribute__((aligned(16))) unsigned short lds[65536];  // 128 KiB

  int tid = threadIdx.x;
  int lane = tid & 63;
  int w = tid >> 6;
  int wm = w >> 2;        // 0..1 -> rows wm*128
  int wn = w & 3;         // 0..3 -> cols wn*64
  int l16 = lane & 15;
  int lk = lane >> 4;

  // ---- 2D XCD slab mapping (bijective; grid = 1536 = 8 XCD * 4 tm * 48 tn) ----
  int bid = blockIdx.x;
  int xcd = bid & 7;
  int local = bid >> 3;       // 0..191
  int r = local >> 5;         // 0..5 tn-round
  int i = local & 31;         // 0..31 co-resident slot
  int tm = (xcd << 2) + (i >> 3);
  int tn = (r << 3) + (i & 7);
  int m0 = tm << 8, n0 = tn << 8;

  // ---- staging source: pre-swizzled global col (3-bit XOR by row&7) ----
  int rp = tid >> 3;
  int ce = ((tid & 7) << 3) ^ ((rp & 7) << 3);
  const unsigned short* aSrc = A + (size_t)(m0 + rp) * KDIM + ce;
  const unsigned short* bSrc = W + (size_t)(n0 + rp) * KDIM + ce;
  int tid8 = tid * 8;

#define STA(b, h, kt) do { \
  __builtin_amdgcn_global_load_lds((GAS void*)(aSrc + (size_t)((h)*128) * KDIM + (kt)*64), \
      (LAS void*)(lds + (b)*16384 + (h)*8192 + tid8), 16, 0, 0); \
  __builtin_amdgcn_global_load_lds((GAS void*)(aSrc + (size_t)((h)*128 + 64) * KDIM + (kt)*64), \
      (LAS void*)(lds + (b)*16384 + (h)*8192 + 4096 + tid8), 16, 0, 0); } while (0)
#define STB(b, h, kt) do { \
  __builtin_amdgcn_global_load_lds((GAS void*)(bSrc + (size_t)((h)*128) * KDIM + (kt)*64), \
      (LAS void*)(lds + 32768 + (b)*16384 + (h)*8192 + tid8), 16, 0, 0); \
  __builtin_amdgcn_global_load_lds((GAS void*)(bSrc + (size_t)((h)*128 + 64) * KDIM + (kt)*64), \
      (LAS void*)(lds + 32768 + (b)*16384 + (h)*8192 + 4096 + tid8), 16, 0, 0); } while (0)

  // ---- fragment read addressing: R3 pattern (0 conflicts measured) ----
  int colbase = (lk << 3) ^ ((l16 & 7) << 3);
  int aRd = wm * 8192 + l16 * 64 + colbase;
  int bRd = (wn >> 1) * 8192 + (wn & 1) * 4096 + l16 * 64 + colbase;

#define RD_A(c, mi, ks) (*(const bf16x8*)(lds + (c)*16384 + (((aRd) + (mi)*1024) ^ ((ks)*32))))
#define RD_B(c, nj, ks) (*(const bf16x8*)(lds + 32768 + (c)*16384 + (((bRd) + (nj)*1024) ^ ((ks)*32))))

  bf16x8 av[8][2];
  bf16x8 bv[4][2];
  f32x4 acc[8][4] = {};

#define RP1(c) do { \
  bv[0][0]=RD_B(c,0,0); bv[0][1]=RD_B(c,0,1); bv[1][0]=RD_B(c,1,0); bv[1][1]=RD_B(c,1,1); \
  bv[2][0]=RD_B(c,2,0); bv[2][1]=RD_B(c,2,1); bv[3][0]=RD_B(c,3,0); bv[3][1]=RD_B(c,3,1); \
  av[0][0]=RD_A(c,0,0); av[0][1]=RD_A(c,0,1); av[1][0]=RD_A(c,1,0); av[1][1]=RD_A(c,1,1); } while (0)
#define RP2(c) do { \
  av[2][0]=RD_A(c,2,0); av[2][1]=RD_A(c,2,1); av[3][0]=RD_A(c,3,0); av[3][1]=RD_A(c,3,1); \
  av[4][0]=RD_A(c,4,0); av[4][1]=RD_A(c,4,1); av[5][0]=RD_A(c,5,0); av[5][1]=RD_A(c,5,1); } while (0)
#define RP3(c) do { \
  av[6][0]=RD_A(c,6,0); av[6][1]=RD_A(c,6,1); av[7][0]=RD_A(c,7,0); av[7][1]=RD_A(c,7,1); } while (0)

#define MFMA2(mi, nj) do { \
  acc[mi][nj] = __builtin_amdgcn_mfma_f32_16x16x32_bf16(av[mi][0], bv[nj][0], acc[mi][nj], 0, 0, 0); \
  acc[mi][nj] = __builtin_amdgcn_mfma_f32_16x16x32_bf16(av[mi][1], bv[nj][1], acc[mi][nj], 0, 0, 0); } while (0)
#define MM(mi) do { MFMA2(mi,0); MFMA2(mi,1); MFMA2(mi,2); MFMA2(mi,3); } while (0)

  // K-tile with in-window prefetch. c = buffer; ka staged into !c A1 at P1;
  // kb (kt+2) staged into c at P2..P4. RP1(c) was prefetched in prev P4.
#define KTILE(c, ka, kb) do { \
  STA(!(c), 1, ka); \
  BAR(); LGKM0(); PRIO(1); MM(0); MM(1); RP2(c); PRIO(0); SB0(); BAR(); \
  STB(c, 0, kb); \
  BAR(); LGKM0(); PRIO(1); MM(2); MM(3); RP3(c); PRIO(0); SB0(); BAR(); \
  STB(c, 1, kb); \
  BAR(); LGKM0(); PRIO(1); MM(4); MM(5); PRIO(0); SB0(); BAR(); \
  STA(c, 0, kb); VMC6(); \
  BAR(); SB0(); PRIO(1); MM(6); MM(7); RP1(!(c)); PRIO(0); SB0(); BAR(); } while (0)

  // ---- prologue: kt0 full -> buf0, kt1 (B0,B1,A0) -> buf1; drain; prefetch ----
  STB(0, 0, 0); STB(0, 1, 0); STA(0, 0, 0); STA(0, 1, 0);
  STB(1, 0, 1); STB(1, 1, 1); STA(1, 0, 1);
  VMC0();
  BAR();
  RP1(0);

  // ---- main loop: 31 iters x 2 K-tiles (kt 0..61) ----
  for (int it = 0; it < 31; ++it) {
    int k1 = 2 * it + 1, k2 = 2 * it + 2, k3 = 2 * it + 3;
    KTILE(0, k1, k2);
    KTILE(1, k2, k3);
  }
  // ---- epilogue: kt62 (buf0; stage only A1 of kt63; full drain), kt63 ----
  STA(1, 1, 63);
  BAR(); LGKM0(); PRIO(1); MM(0); MM(1); RP2(0); PRIO(0); SB0(); BAR();
  BAR(); LGKM0(); PRIO(1); MM(2); MM(3); RP3(0); PRIO(0); SB0(); BAR();
  BAR(); LGKM0(); PRIO(1); MM(4); MM(5); PRIO(0); SB0(); BAR();
  VMC0();
  BAR(); SB0(); PRIO(1); MM(6); MM(7); RP1(1); PRIO(0); SB0(); BAR();
  BAR(); LGKM0(); PRIO(1); MM(0); MM(1); RP2(1); PRIO(0); SB0(); BAR();
  BAR(); LGKM0(); PRIO(1); MM(2); MM(3); RP3(1); PRIO(0); SB0(); BAR();
  BAR(); LGKM0(); PRIO(1); MM(4); MM(5); PRIO(0); SB0(); BAR();
  BAR(); LGKM0(); PRIO(1); MM(6); MM(7); PRIO(0);

  // ---- C write: col = l16 + 16*nj (+ wn*64), row = lk*4 + r + 16*mi (+ wm*128) ----
  int matc = n0 >> 12;
  int ncol = (n0 & 4095) + wn * 64;
  unsigned short* O = out + (size_t)matc * M_TOK * HIDDEN;
  float bb[4];
#pragma unroll
  for (int nj = 0; nj < 4; ++nj) bb[nj] = bias[n0 + wn * 64 + nj * 16 + l16];
#pragma unroll
  for (int mi = 0; mi < 8; ++mi) {
#pragma unroll
    for (int rr = 0; rr < 4; ++rr) {
      int row = m0 + wm * 128 + mi * 16 + lk * 4 + rr;
      size_t rb = (size_t)row * HIDDEN + ncol + l16;
#pragma unroll
      for (int nj = 0; nj < 4; ++nj)
        O[rb + nj * 16] = f2bf(acc[mi][nj][rr] + bb[nj]);
    }
  }
}

// ---------- per-token 32x32 head attention ----------
__global__ __launch_bounds__(256) void attn_kernel(const unsigned short* __restrict__ qkv,
                                                   float* __restrict__ out) {
  __shared__ float sQ[32 * 132];
  __shared__ float sK[32 * 132];
  __shared__ float sV[32 * 132];
  __shared__ float sP[32 * 33];

  int m = blockIdx.x;
  int tid = threadIdx.x;
  const unsigned short* gq = qkv + (size_t)m * HIDDEN;
  const unsigned short* gk = gq + (size_t)M_TOK * HIDDEN;
  const unsigned short* gv = gk + (size_t)M_TOK * HIDDEN;

  int row = tid >> 3;
  int cb = (tid & 7) << 4;
  int go = row * 128 + cb;
  int lo = row * 132 + cb;
  {
    u16x8 x0 = *(const u16x8*)(gq + go);
    u16x8 x1 = *(const u16x8*)(gq + go + 8);
#pragma unroll
    for (int j = 0; j < 8; ++j) { sQ[lo + j] = bf2f(x0[j]); sQ[lo + 8 + j] = bf2f(x1[j]); }
    x0 = *(const u16x8*)(gk + go);
    x1 = *(const u16x8*)(gk + go + 8);
#pragma unroll
    for (int j = 0; j < 8; ++j) { sK[lo + j] = bf2f(x0[j]); sK[lo + 8 + j] = bf2f(x1[j]); }
    x0 = *(const u16x8*)(gv + go);
    x1 = *(const u16x8*)(gv + go + 8);
#pragma unroll
    for (int j = 0; j < 8; ++j) { sV[lo + j] = bf2f(x0[j]); sV[lo + 8 + j] = bf2f(x1[j]); }
  }
  __syncthreads();

  int h = tid >> 3;
  int t4 = (tid & 7) << 2;
  const f32x4* qr = (const f32x4*)(sQ + h * 132);
  const f32x4* k0 = (const f32x4*)(sK + (t4 + 0) * 132);
  const f32x4* k1 = (const f32x4*)(sK + (t4 + 1) * 132);
  const f32x4* k2 = (const f32x4*)(sK + (t4 + 2) * 132);
  const f32x4* k3 = (const f32x4*)(sK + (t4 + 3) * 132);
  float s0 = 0.f, s1 = 0.f, s2 = 0.f, s3 = 0.f;
#pragma unroll
  for (int d = 0; d < 32; ++d) {
    f32x4 q = qr[d];
    f32x4 a = k0[d]; s0 += q.x * a.x + q.y * a.y + q.z * a.z + q.w * a.w;
    f32x4 b = k1[d]; s1 += q.x * b.x + q.y * b.y + q.z * b.z + q.w * b.w;
    f32x4 c = k2[d]; s2 += q.x * c.x + q.y * c.y + q.z * c.z + q.w * c.w;
    f32x4 e = k3[d]; s3 += q.x * e.x + q.y * e.y + q.z * e.z + q.w * e.w;
  }
  const float scale = 0.08838834764831845f;  // 1/sqrt(128)
  s0 *= scale; s1 *= scale; s2 *= scale; s3 *= scale;
  float mx = fmaxf(fmaxf(s0, s1), fmaxf(s2, s3));
  mx = fmaxf(mx, __shfl_xor(mx, 1));
  mx = fmaxf(mx, __shfl_xor(mx, 2));
  mx = fmaxf(mx, __shfl_xor(mx, 4));
  float e0 = __expf(s0 - mx), e1 = __expf(s1 - mx), e2 = __expf(s2 - mx), e3 = __expf(s3 - mx);
  float sum = e0 + e1 + e2 + e3;
  sum += __shfl_xor(sum, 1);
  sum += __shfl_xor(sum, 2);
  sum += __shfl_xor(sum, 4);
  float inv = 1.0f / sum;
  sP[h * 33 + t4 + 0] = e0 * inv;
  sP[h * 33 + t4 + 1] = e1 * inv;
  sP[h * 33 + t4 + 2] = e2 * inv;
  sP[h * 33 + t4 + 3] = e3 * inv;
  __syncthreads();

  int d0 = (tid & 7) << 4;
  f32x4 o0 = {0.f, 0.f, 0.f, 0.f}, o1 = o0, o2 = o0, o3 = o0;
  const float* pr = sP + h * 33;
#pragma unroll
  for (int t = 0; t < 32; ++t) {
    float p = pr[t];
    const f32x4* vr = (const f32x4*)(sV + t * 132 + d0);
    o0 += p * vr[0];
    o1 += p * vr[1];
    o2 += p * vr[2];
    o3 += p * vr[3];
  }
  f32x4* op = (f32x4*)(out + (size_t)m * HIDDEN + h * 128 + d0);
  op[0] = o0; op[1] = o1; op[2] = o2; op[3] = o3;
}

extern "C" void kernel_launch(void* const* d_in, const int* in_sizes, int n_in,
                              void* d_out, int out_size, void* d_ws, size_t ws_size,
                              hipStream_t stream) {
  const float* hs = (const float*)d_in[0];
  const float* wq = (const float*)d_in[1];
  const float* bq = (const float*)d_in[2];
  const float* wk = (const float*)d_in[3];
  const float* bk = (const float*)d_in[4];
  const float* wv = (const float*)d_in[5];
  const float* bv = (const float*)d_in[6];
  // wl/bl latent projection: unused by output — skipped.

  char* ws = (char*)d_ws;
  const size_t HS_OFF = 0;                    // 64 MiB
  const size_t W_OFF = 67108864;              // 96 MiB
  const size_t QKV_OFF = 167772160;           // 192 MiB
  const size_t BIAS_OFF = 369098752;          // 48 KiB
  const size_t NEED = 369147904;
  if (ws_size < NEED) return;

  unsigned short* hsb = (unsigned short*)(ws + HS_OFF);
  unsigned short* wb = (unsigned short*)(ws + W_OFF);
  unsigned short* qkv = (unsigned short*)(ws + QKV_OFF);
  float* bias = (float*)(ws + BIAS_OFF);

  cvt_fused<<<41008, 256, 0, stream>>>(hs, wq, wk, wv, bq, bk, bv, hsb, wb, bias);
  gemm_qkv<<<1536, 512, 0, stream>>>(hsb, wb, bias, qkv);   // 8 XCD x 4 tm x 48 tn
  attn_kernel<<<8192, 256, 0, stream>>>(qkv, (float*)d_out);
}